// Round 12
// baseline (294.384 us; speedup 1.0000x reference)
//
#include <hip/hip_runtime.h>
#include <hip/hip_bf16.h>
#include <stdint.h>

#define DEVINL __device__ __forceinline__

using bf16x8 = __attribute__((ext_vector_type(8))) short;
using f32x4  = __attribute__((ext_vector_type(4))) float;

static constexpr int NPTS = 50000;
static constexpr int NPAD = 50176;         // 196 * 256
static constexpr int DIM  = 768;
static constexpr int DATT = 128;
static constexpr int NRB  = NPAD / 128;    // 392 row blocks (gate / partial)
static constexpr int NSMB = 49;            // softmax partial blocks (49*1024=50176)

DEVINL ushort f2b(float f) {               // RNE float->bf16 (finite inputs)
  uint32_t u = __float_as_uint(f);
  u += 0x7fffu + ((u >> 16) & 1u);
  return (ushort)(u >> 16);
}
DEVINL float b2f(ushort u) { return __uint_as_float(((uint32_t)u) << 16); }
DEVINL uint32_t cvtpk(float lo, float hi) {
  union { __hip_bfloat162 h2; uint32_t u; } c;
  c.h2 = __float22bfloat162_rn(float2{lo, hi});
  return c.u;
}

DEVINL void gload_lds16(const void* g, void* l) {
  __builtin_amdgcn_global_load_lds((const __attribute__((address_space(1))) void*)g,
                                   (__attribute__((address_space(3))) void*)l,
                                   16, 0, 0);
}

// ---------------- K0: fp32 -> bf16 for the three weight matrices --------------
__global__ void cvt_weights_kernel(const float* __restrict__ Wf, const float* __restrict__ Wa,
                                   const float* __restrict__ Wb,
                                   ushort* __restrict__ wfb, ushort* __restrict__ wab,
                                   ushort* __restrict__ wbb) {
  const int NF = DIM * DIM / 8, NA = DATT * DIM / 8;
  int i = blockIdx.x * blockDim.x + threadIdx.x;
  const float* src; ushort* dst; int j;
  if (i < NF)               { src = Wf; dst = wfb; j = i; }
  else if (i < NF + NA)     { src = Wa; dst = wab; j = i - NF; }
  else if (i < NF + 2 * NA) { src = Wb; dst = wbb; j = i - NF - NA; }
  else return;
  const float4* s4 = (const float4*)src;
  float4 v0 = s4[(long)j * 2];
  float4 v1 = s4[(long)j * 2 + 1];
  ushort4 o0 = { f2b(v0.x), f2b(v0.y), f2b(v0.z), f2b(v0.w) };
  ushort4 o1 = { f2b(v1.x), f2b(v1.y), f2b(v1.z), f2b(v1.w) };
  ((ushort4*)dst)[(long)j * 2]     = o0;
  ((ushort4*)dst)[(long)j * 2 + 1] = o1;
}

// ---------------- K1: h = relu(x @ Wf^T + bias), x read fp32, reg-staged cvt --
// R8 geometry: BM=256, BN=128, BK=64, 8 waves (4M x 2N), 3 x 48KB LDS,
// identical zero-conflict XOR layout. B via gload_lds (unchanged).
// A: fp32 global->reg (8x float4/thread, issued one step early) ->
//    cvt_pk -> 4x swizzled ds_write_b128 (T14 issue-early/write-late).
// Step t: vmcnt(2) [A(t+1) regs landed; B(t+1) 2 still in flight] ->
//   WRITE_A(t+1)->buf[(t+1)%3] -> issue A(t+2) regs + B(t+2) gload ->
//   compute tile t from buf[t%3] -> vmcnt(10) [B(t+1) done; t+2 in flight]
//   -> lgkmcnt(0) -> ONE barrier/step.
// FIFO audit: outstanding at step-t start = A(t+1)8 + B(t+1)2 = 10. All vmcnt
// asms carry "memory" so the compiler cannot hoist unrelated VMEM (bias) above.
// OOB rows clamp to NPTS-1 (finite; masked downstream by gate/partial).
__global__ __launch_bounds__(512)
void gemm_h_fused(const float* __restrict__ X, const ushort* __restrict__ Wfb,
                  const float* __restrict__ bias, ushort* __restrict__ H) {
  __shared__ ushort lds[3][24576];   // per buf: A[256][64] @0 (32KB), B[128][64] @16384

  const int tid  = threadIdx.x;
  const int wid  = tid >> 6;           // 0..7
  const int lane = tid & 63;

  const int bid  = blockIdx.x;                       // 0..1175
  const int wgid = (bid & 7) * 147 + (bid >> 3);     // chunked XCD swizzle (1176%8==0)
  const int row0 = (wgid / 6) * 256;
  const int col0 = (wgid % 6) * 128;

  const int wrow = (wid >> 1) * 64;    // 0,64,128,192
  const int wcol = (wid & 1) * 64;     // 0,64

  // ---- B staging (bf16, gload_lds, pre-swizzled source) — R8 verbatim ----
  const int srow = lane >> 3;
  const int scol = ((lane & 7) ^ (lane >> 3)) * 8;
  const ushort* Bbase = Wfb + (long)col0 * DIM;
  auto STAGE_B = [&](int t, int buf) {   // 2 gload_lds per thread (16KB)
    const int k0 = t * 64;
#pragma unroll
    for (int i = 0; i < 2; ++i) {
      const int ch = i * 8 + wid;
      gload_lds16(Bbase + (long)(ch * 8 + srow) * DIM + k0 + scol,
                  &lds[buf][16384 + ch * 512]);
    }
  };

  // ---- A staging: thread -> (row ar, j-half aj0); 32 consecutive floats ----
  const int ar  = tid >> 1;            // 0..255
  const int aj0 = (tid & 1) * 4;       // chunk base 0 or 4
  const int arow = row0 + ar;
  const int asrc = arow < NPTS ? arow : NPTS - 1;
  const float* Abase = X + (long)asrc * DIM + aj0 * 8;

  float4 areg[8];
  auto LOAD_A = [&](int t) {           // 8x float4 (128B contiguous per thread)
    const float* s = Abase + t * 64;
#pragma unroll
    for (int i = 0; i < 8; ++i) areg[i] = *(const float4*)(s + i * 4);
  };
  auto WRITE_A = [&](int buf) {        // cvt + 4 swizzled ds_write_b128
#pragma unroll
    for (int w = 0; w < 4; ++w) {
      const int j = aj0 + w;
      const int off = ar * 64 + ((j ^ (ar & 7)) << 3);   // ushort offset
      uint4 o;
      o.x = cvtpk(areg[2 * w].x,     areg[2 * w].y);
      o.y = cvtpk(areg[2 * w].z,     areg[2 * w].w);
      o.z = cvtpk(areg[2 * w + 1].x, areg[2 * w + 1].y);
      o.w = cvtpk(areg[2 * w + 1].z, areg[2 * w + 1].w);
      *(uint4*)&lds[buf][off] = o;
    }
  };

  f32x4 acc[4][4] = {};

  // prologue
  LOAD_A(0); STAGE_B(0, 0);                            // out: 8 + 2
  asm volatile("s_waitcnt vmcnt(2)" ::: "memory");     // A0 regs ready
  WRITE_A(0);                                          // -> buf0
  LOAD_A(1); STAGE_B(1, 1);                            // out: 2(B0) + 10
  asm volatile("s_waitcnt vmcnt(10)" ::: "memory");    // B0 landed
  asm volatile("s_waitcnt lgkmcnt(0)" ::: "memory");   // A0 writes visible
  __builtin_amdgcn_s_barrier();

#pragma unroll 1
  for (int t = 0; t < 12; ++t) {
    const int cb = t % 3;
    if (t < 11) {
      asm volatile("s_waitcnt vmcnt(2)" ::: "memory"); // A(t+1) regs landed
      WRITE_A((t + 1) % 3);                            // buf free since step t-1
    }
    if (t < 10) {
      LOAD_A(t + 2);
      STAGE_B(t + 2, (t + 2) % 3);                     // buf free (read at t-1)
    }
    // compute tile t
    {
      const ushort* Ab = &lds[cb][0];
      const ushort* Bb = &lds[cb][16384];
#pragma unroll
      for (int kk = 0; kk < 2; ++kk) {
        const int j = kk * 4 + (lane >> 4);
        bf16x8 a[4], b[4];
#pragma unroll
        for (int m = 0; m < 4; ++m) {
          const int ra = wrow + m * 16 + (lane & 15);
          a[m] = *(const bf16x8*)(Ab + ra * 64 + ((j ^ (ra & 7)) << 3));
        }
#pragma unroll
        for (int n = 0; n < 4; ++n) {
          const int rb = wcol + n * 16 + (lane & 15);
          b[n] = *(const bf16x8*)(Bb + rb * 64 + ((j ^ (rb & 7)) << 3));
        }
        __builtin_amdgcn_s_setprio(1);
#pragma unroll
        for (int n = 0; n < 4; ++n)
#pragma unroll
          for (int m = 0; m < 4; ++m)
            acc[m][n] = __builtin_amdgcn_mfma_f32_16x16x32_bf16(a[m], b[n], acc[m][n], 0, 0, 0);
        __builtin_amdgcn_s_setprio(0);
      }
    }
    if (t < 10) {
      asm volatile("s_waitcnt vmcnt(10)" ::: "memory"); // B(t+1) done; t+2 flying
    } else if (t == 10) {
      asm volatile("s_waitcnt vmcnt(0)" ::: "memory");  // drain B(11)
    }
    asm volatile("s_waitcnt lgkmcnt(0)" ::: "memory");  // publish WRITE_A(t+1)
    __builtin_amdgcn_s_barrier();
  }

  __builtin_amdgcn_sched_barrier(0);
  const int lq = lane >> 4;
  const int lc = lane & 15;
#pragma unroll
  for (int n = 0; n < 4; ++n) {
    const int cg = col0 + wcol + n * 16 + lc;
    const float bv = bias[cg];
#pragma unroll
    for (int m = 0; m < 4; ++m) {
      const int rg = row0 + wrow + m * 16 + lq * 4;
#pragma unroll
      for (int r2 = 0; r2 < 4; ++r2) {
        float v = acc[m][n][r2] + bv;
        v = fmaxf(v, 0.0f);
        H[(long)(rg + r2) * DIM + cg] = f2b(v);
      }
    }
  }
}

// ---------------- K2: logits[n] = sum_k relu(h·Wa^T)·sigmoid(h·Wb^T)·Wc -------
__global__ __launch_bounds__(512)
void gate_kernel(const ushort* __restrict__ Hm, const ushort* __restrict__ Wa,
                 const ushort* __restrict__ Wb, const float* __restrict__ Wc,
                 float* __restrict__ logits) {
  __shared__ ushort Hs [128 * 64];
  __shared__ ushort Was[128 * 64];
  __shared__ ushort Wbs[128 * 64];
  const int tid  = threadIdx.x;
  const int wid  = tid >> 6;           // 0..7
  const int lane = tid & 63;
  const int row0 = blockIdx.x * 128;

  f32x4 fa[8] = {};
  f32x4 fb[8] = {};

  const int ld_r = lane >> 3;
  const int ld_c = (lane & 7) * 8;

  for (int k0 = 0; k0 < DIM; k0 += 64) {
    __syncthreads();
#pragma unroll
    for (int i = 0; i < 2; ++i) {
      const int ch = i * 8 + wid;      // 0..15
      const int r  = ch * 8 + ld_r;    // 0..127
      gload_lds16(Hm + (long)(row0 + r) * DIM + k0 + ld_c, Hs  + ch * 512);
      gload_lds16(Wa + (long)r * DIM        + k0 + ld_c, Was + ch * 512);
      gload_lds16(Wb + (long)r * DIM        + k0 + ld_c, Wbs + ch * 512);
    }
    __syncthreads();
#pragma unroll
    for (int kk = 0; kk < 2; ++kk) {
      const int kc = kk * 32 + (lane >> 4) * 8;
      bf16x8 h = *(const bf16x8*)(Hs + (wid * 16 + (lane & 15)) * 64 + kc);
#pragma unroll
      for (int n = 0; n < 8; ++n) {
        bf16x8 wa = *(const bf16x8*)(Was + (n * 16 + (lane & 15)) * 64 + kc);
        bf16x8 wb = *(const bf16x8*)(Wbs + (n * 16 + (lane & 15)) * 64 + kc);
        fa[n] = __builtin_amdgcn_mfma_f32_16x16x32_bf16(h, wa, fa[n], 0, 0, 0);
        fb[n] = __builtin_amdgcn_mfma_f32_16x16x32_bf16(h, wb, fb[n], 0, 0, 0);
      }
    }
  }

  const int lc = lane & 15;
  const int lq = lane >> 4;
  float g[4];
#pragma unroll
  for (int r = 0; r < 4; ++r) {
    float s = 0.f;
#pragma unroll
    for (int n = 0; n < 8; ++n) {
      float av = fmaxf(fa[n][r], 0.f);
      float sg = 1.f / (1.f + expf(-fb[n][r]));
      s += av * sg * Wc[n * 16 + lc];
    }
    s += __shfl_xor(s, 1);
    s += __shfl_xor(s, 2);
    s += __shfl_xor(s, 4);
    s += __shfl_xor(s, 8);
    g[r] = s;
  }
  if (lc == 0) {
    const int rbase = row0 + wid * 16 + lq * 4;
#pragma unroll
    for (int r = 0; r < 4; ++r) {
      const int nidx = rbase + r;
      if (nidx < NPTS) logits[nidx] = g[r];
    }
  }
}

// ---------------- K3a: per-block softmax partials (49 blocks x 1024) ----------
__global__ __launch_bounds__(1024)
void softmax_part_kernel(const float* __restrict__ logits, float* __restrict__ part2) {
  __shared__ float red[1024];
  const int tid = threadIdx.x;
  const int n = blockIdx.x * 1024 + tid;
  const float v = (n < NPTS) ? logits[n] : -1e30f;
  red[tid] = v; __syncthreads();
  for (int s = 512; s > 0; s >>= 1) {
    if (tid < s) red[tid] = fmaxf(red[tid], red[tid + s]);
    __syncthreads();
  }
  const float m = red[0];
  __syncthreads();
  red[tid] = (n < NPTS) ? expf(v - m) : 0.f;
  __syncthreads();
  for (int s = 512; s > 0; s >>= 1) {
    if (tid < s) red[tid] += red[tid + s];
    __syncthreads();
  }
  if (tid == 0) { part2[blockIdx.x * 2] = m; part2[blockIdx.x * 2 + 1] = red[0]; }
}

// ---------------- K3b: combine partials (1 wave, deterministic trees) ---------
__global__ void softmax_comb_kernel(const float* __restrict__ part2,
                                    float* __restrict__ stats) {
  const int l = threadIdx.x;           // 0..63
  float m = (l < NSMB) ? part2[l * 2]     : -1e30f;
  float s = (l < NSMB) ? part2[l * 2 + 1] : 0.f;
  float M = m;
  for (int o = 32; o > 0; o >>= 1) M = fmaxf(M, __shfl_xor(M, o));
  float sc = s * expf(m - M);          // padding: 0 * 0 = 0
  for (int o = 32; o > 0; o >>= 1) sc += __shfl_xor(sc, o);
  if (l == 0) { stats[0] = M; stats[1] = sc; }
}

// ---------------- K4: partial[b][d] = sum_{n in chunk} exp(l_n - m) * h[n][d] --
__global__ __launch_bounds__(192)
void weighted_partial_kernel(const ushort* __restrict__ Hm, const float* __restrict__ logits,
                             const float* __restrict__ stats, float* __restrict__ part) {
  __shared__ float w[128];
  const int b = blockIdx.x, tid = threadIdx.x;
  const int n0 = b * 128;
  if (tid < 128) {
    const int n = n0 + tid;
    w[tid] = (n < NPTS) ? expf(logits[n] - stats[0]) : 0.f;
  }
  __syncthreads();
  float4 acc = {0.f, 0.f, 0.f, 0.f};
  const ushort* hp = Hm + (long)n0 * DIM + tid * 4;
#pragma unroll 4
  for (int r = 0; r < 128; ++r) {
    const float wr = w[r];
    ushort4 v = *(const ushort4*)(hp + (long)r * DIM);
    acc.x += wr * b2f(v.x);
    acc.y += wr * b2f(v.y);
    acc.z += wr * b2f(v.z);
    acc.w += wr * b2f(v.w);
  }
  ((float4*)(part + (long)b * DIM))[tid] = acc;
}

// ---------------- K5: out[d] = (sum_b part[b][d]) / sum_exp --------------------
__global__ void final_reduce_kernel(const float* __restrict__ part,
                                    const float* __restrict__ stats,
                                    float* __restrict__ out) {
  const int c = blockIdx.x * blockDim.x + threadIdx.x;
  if (c >= DIM) return;
  float s = 0.f;
  for (int b = 0; b < NRB; ++b) s += part[(long)b * DIM + c];
  out[c] = s / stats[1];
}

extern "C" void kernel_launch(void* const* d_in, const int* in_sizes, int n_in,
                              void* d_out, int out_size, void* d_ws, size_t ws_size,
                              hipStream_t stream) {
  const float* x  = (const float*)d_in[0];
  const float* Wf = (const float*)d_in[1];
  const float* bf = (const float*)d_in[2];
  const float* Wa = (const float*)d_in[3];
  const float* Wb = (const float*)d_in[4];
  const float* Wc = (const float*)d_in[5];
  float* out = (float*)d_out;

  char* p = (char*)d_ws;
  ushort* hb  = (ushort*)p; p += (size_t)NPAD * DIM * 2;   // 77.1 MB
  ushort* wfb = (ushort*)p; p += (size_t)DIM * DIM * 2;
  ushort* wab = (ushort*)p; p += (size_t)DATT * DIM * 2;
  ushort* wbb = (ushort*)p; p += (size_t)DATT * DIM * 2;
  float* logits = (float*)p; p += (size_t)NPAD * 4;
  float* stats  = (float*)p; p += 256;
  float* part2  = (float*)p; p += 1024;
  float* part   = (float*)p; p += (size_t)NRB * DIM * 4;

  cvt_weights_kernel<<<384, 256, 0, stream>>>(Wf, Wa, Wb, wfb, wab, wbb);

  gemm_h_fused<<<196 * 6, 512, 0, stream>>>(x, wfb, bf, hb);
  gate_kernel<<<NRB, 512, 0, stream>>>(hb, wab, wbb, Wc, logits);
  softmax_part_kernel<<<NSMB, 1024, 0, stream>>>(logits, part2);
  softmax_comb_kernel<<<1, 64, 0, stream>>>(part2, stats);
  weighted_partial_kernel<<<NRB, 192, 0, stream>>>(hb, logits, stats, part);
  final_reduce_kernel<<<3, 256, 0, stream>>>(part, stats, out);
}

// Round 13
// 217.180 us; speedup vs baseline: 1.3555x; 1.3555x over previous
//
#include <hip/hip_runtime.h>
#include <hip/hip_bf16.h>
#include <stdint.h>

#define DEVINL __device__ __forceinline__

using bf16x8 = __attribute__((ext_vector_type(8))) short;
using f32x4  = __attribute__((ext_vector_type(4))) float;

static constexpr int NPTS = 50000;
static constexpr int NPAD = 50176;         // 196 * 256
static constexpr int DIM  = 768;
static constexpr int DATT = 128;
static constexpr int NRB  = NPAD / 128;    // 392 row blocks (gate / partial)

DEVINL ushort f2b(float f) {               // RNE float->bf16 (finite inputs)
  uint32_t u = __float_as_uint(f);
  u += 0x7fffu + ((u >> 16) & 1u);
  return (ushort)(u >> 16);
}
DEVINL float b2f(ushort u) { return __uint_as_float(((uint32_t)u) << 16); }
DEVINL uint32_t pk2(float lo, float hi) {
  return (uint32_t)f2b(lo) | ((uint32_t)f2b(hi) << 16);
}

DEVINL void gload_lds16(const void* g, void* l) {
  __builtin_amdgcn_global_load_lds((const __attribute__((address_space(1))) void*)g,
                                   (__attribute__((address_space(3))) void*)l,
                                   16, 0, 0);
}

// ---------------- K0a: fp32 -> bf16 for x, one-shot, 16 floats/thread ---------
// 9408 blocks x 256 threads x 16 = 38,535,168 = NPAD*DIM exactly.
__global__ __launch_bounds__(256)
void cvt_x_kernel(const float* __restrict__ src, ushort* __restrict__ dst) {
  const long i = ((long)blockIdx.x * 256 + threadIdx.x) * 16;   // float index
  const long NS = (long)NPTS * DIM;
  float4 v[4];
  if (i + 16 <= NS) {                       // fast path (bulk)
#pragma unroll
    for (int k = 0; k < 4; ++k) v[k] = *(const float4*)(src + i + k * 4);
  } else {                                  // boundary / padded tail
#pragma unroll
    for (int k = 0; k < 4; ++k) {
      float t0 = (i + k * 4 + 0 < NS) ? src[i + k * 4 + 0] : 0.f;
      float t1 = (i + k * 4 + 1 < NS) ? src[i + k * 4 + 1] : 0.f;
      float t2 = (i + k * 4 + 2 < NS) ? src[i + k * 4 + 2] : 0.f;
      float t3 = (i + k * 4 + 3 < NS) ? src[i + k * 4 + 3] : 0.f;
      v[k] = {t0, t1, t2, t3};
    }
  }
  uint4 o0, o1;
  o0.x = pk2(v[0].x, v[0].y); o0.y = pk2(v[0].z, v[0].w);
  o0.z = pk2(v[1].x, v[1].y); o0.w = pk2(v[1].z, v[1].w);
  o1.x = pk2(v[2].x, v[2].y); o1.y = pk2(v[2].z, v[2].w);
  o1.z = pk2(v[3].x, v[3].y); o1.w = pk2(v[3].z, v[3].w);
  uint4* d = (uint4*)(dst + i);
  d[0] = o0;
  d[1] = o1;
}

// ---------------- K0b: fp32 -> bf16 for the three weight matrices -------------
__global__ void cvt_weights_kernel(const float* __restrict__ Wf, const float* __restrict__ Wa,
                                   const float* __restrict__ Wb,
                                   ushort* __restrict__ wfb, ushort* __restrict__ wab,
                                   ushort* __restrict__ wbb) {
  const int NF = DIM * DIM / 8, NA = DATT * DIM / 8;
  int i = blockIdx.x * blockDim.x + threadIdx.x;
  const float* src; ushort* dst; int j;
  if (i < NF)               { src = Wf; dst = wfb; j = i; }
  else if (i < NF + NA)     { src = Wa; dst = wab; j = i - NF; }
  else if (i < NF + 2 * NA) { src = Wb; dst = wbb; j = i - NF - NA; }
  else return;
  const float4* s4 = (const float4*)src;
  float4 v0 = s4[(long)j * 2];
  float4 v1 = s4[(long)j * 2 + 1];
  ushort4 o0 = { f2b(v0.x), f2b(v0.y), f2b(v0.z), f2b(v0.w) };
  ushort4 o1 = { f2b(v1.x), f2b(v1.y), f2b(v1.z), f2b(v1.w) };
  ((ushort4*)dst)[(long)j * 2]     = o0;
  ((ushort4*)dst)[(long)j * 2 + 1] = o1;
}

// ---------------- K1: h = relu(x @ Wf^T + bias) — best measured (87.5us) ------
__global__ __launch_bounds__(512)
void gemm_h_kernel(const ushort* __restrict__ A, const ushort* __restrict__ B,
                   const float* __restrict__ bias, ushort* __restrict__ H) {
  __shared__ ushort lds[3][24576];   // per buf: A[256][64] @0, B[128][64] @16384

  const int tid  = threadIdx.x;
  const int wid  = tid >> 6;           // 0..7
  const int lane = tid & 63;

  const int bid  = blockIdx.x;                       // 0..1175
  const int wgid = (bid & 7) * 147 + (bid >> 3);     // chunked XCD swizzle (1176%8==0)
  const int row0 = (wgid / 6) * 256;
  const int col0 = (wgid % 6) * 128;

  const int wrow = (wid >> 1) * 64;    // 0,64,128,192
  const int wcol = (wid & 1) * 64;     // 0,64

  const int srow = lane >> 3;                          // 0..7
  const int scol = ((lane & 7) ^ (lane >> 3)) * 8;     // pre-swizzled src col-chunk

  const ushort* Abase = A + (long)row0 * DIM;
  const ushort* Bbase = B + (long)col0 * DIM;

  auto STAGE_A = [&](int t, int buf) {   // 4 gload_lds per thread (32KB)
    const int k0 = t * 64;
#pragma unroll
    for (int i = 0; i < 4; ++i) {
      const int ch = i * 8 + wid;                      // 0..31 (8 rows each)
      gload_lds16(Abase + (long)(ch * 8 + srow) * DIM + k0 + scol,
                  &lds[buf][ch * 512]);
    }
  };
  auto STAGE_B = [&](int t, int buf) {   // 2 gload_lds per thread (16KB)
    const int k0 = t * 64;
#pragma unroll
    for (int i = 0; i < 2; ++i) {
      const int ch = i * 8 + wid;                      // 0..15
      gload_lds16(Bbase + (long)(ch * 8 + srow) * DIM + k0 + scol,
                  &lds[buf][16384 + ch * 512]);
    }
  };

  f32x4 acc[4][4] = {};

  STAGE_A(0, 0); STAGE_B(0, 0);
  STAGE_A(1, 1); STAGE_B(1, 1);
  asm volatile("s_waitcnt vmcnt(6)" ::: "memory");     // tile 0 landed; tile 1 in flight
  __builtin_amdgcn_s_barrier();

  int c = 0;
#pragma unroll 1
  for (int t = 0; t < 12; ++t) {
    const int nb = (c == 0) ? 2 : c - 1;               // (t+2)%3
    const ushort* Ab = &lds[c][0];
    const ushort* Bb = &lds[c][16384];

    // ================= phase 0 : kk=0 =================
    {
      const int j = lane >> 4;                         // k-chunk 0..3
      bf16x8 a[4], b[4];
#pragma unroll
      for (int m = 0; m < 4; ++m) {
        const int ra = wrow + m * 16 + (lane & 15);
        a[m] = *(const bf16x8*)(Ab + ra * 64 + ((j ^ (ra & 7)) << 3));
      }
#pragma unroll
      for (int n = 0; n < 4; ++n) {
        const int rb = wcol + n * 16 + (lane & 15);
        b[n] = *(const bf16x8*)(Bb + rb * 64 + ((j ^ (rb & 7)) << 3));
      }
      if (t < 10) STAGE_A(t + 2, nb);                  // prefetch half 1 of tile t+2
      __builtin_amdgcn_s_barrier();
      asm volatile("s_waitcnt lgkmcnt(0)" ::: "memory");
      __builtin_amdgcn_sched_barrier(0);
      __builtin_amdgcn_s_setprio(1);
#pragma unroll
      for (int n = 0; n < 4; ++n)
#pragma unroll
        for (int m = 0; m < 4; ++m)
          acc[m][n] = __builtin_amdgcn_mfma_f32_16x16x32_bf16(a[m], b[n], acc[m][n], 0, 0, 0);
      __builtin_amdgcn_s_setprio(0);
      __builtin_amdgcn_sched_barrier(0);
      __builtin_amdgcn_s_barrier();
    }
    // ================= phase 1 : kk=1 =================
    {
      const int j = 4 + (lane >> 4);                   // k-chunk 4..7
      bf16x8 a[4], b[4];
#pragma unroll
      for (int m = 0; m < 4; ++m) {
        const int ra = wrow + m * 16 + (lane & 15);
        a[m] = *(const bf16x8*)(Ab + ra * 64 + ((j ^ (ra & 7)) << 3));
      }
#pragma unroll
      for (int n = 0; n < 4; ++n) {
        const int rb = wcol + n * 16 + (lane & 15);
        b[n] = *(const bf16x8*)(Bb + rb * 64 + ((j ^ (rb & 7)) << 3));
      }
      if (t < 10) STAGE_B(t + 2, nb);                  // prefetch half 2 of tile t+2
      if (t < 10) {
        asm volatile("s_waitcnt vmcnt(6)" ::: "memory"); // t+1 landed; t+2 in flight
      } else if (t == 10) {
        asm volatile("s_waitcnt vmcnt(0)" ::: "memory"); // drain tile 11
      }
      __builtin_amdgcn_s_barrier();
      asm volatile("s_waitcnt lgkmcnt(0)" ::: "memory");
      __builtin_amdgcn_sched_barrier(0);
      __builtin_amdgcn_s_setprio(1);
#pragma unroll
      for (int n = 0; n < 4; ++n)
#pragma unroll
        for (int m = 0; m < 4; ++m)
          acc[m][n] = __builtin_amdgcn_mfma_f32_16x16x32_bf16(a[m], b[n], acc[m][n], 0, 0, 0);
      __builtin_amdgcn_s_setprio(0);
      __builtin_amdgcn_sched_barrier(0);
      __builtin_amdgcn_s_barrier();
    }
    c = (c == 2) ? 0 : c + 1;
  }

  const int lq = lane >> 4;
  const int lc = lane & 15;
#pragma unroll
  for (int n = 0; n < 4; ++n) {
    const int cg = col0 + wcol + n * 16 + lc;
    const float bv = bias[cg];
#pragma unroll
    for (int m = 0; m < 4; ++m) {
      const int rg = row0 + wrow + m * 16 + lq * 4;
#pragma unroll
      for (int r2 = 0; r2 < 4; ++r2) {
        float v = acc[m][n][r2] + bv;
        v = fmaxf(v, 0.0f);
        H[(long)(rg + r2) * DIM + cg] = f2b(v);
      }
    }
  }
}

// ---------------- K2: gate + block-local softmax stats -------------------------
// Proven gate (33us) + cheap phase B: m_b = max l over this block's 128 rows,
// S_b = sum exp(l - m_b) -> part2[b]. Logits also written (weighted_partial
// needs per-row l). The R11-regressing phase C is NOT here.
__global__ __launch_bounds__(512)
void gate_stats_kernel(const ushort* __restrict__ Hm, const ushort* __restrict__ Wa,
                       const ushort* __restrict__ Wb, const float* __restrict__ Wc,
                       float* __restrict__ logits, float* __restrict__ part2) {
  __shared__ ushort Hs [128 * 64];
  __shared__ ushort Was[128 * 64];
  __shared__ ushort Wbs[128 * 64];
  __shared__ float  l_lds[128];
  __shared__ float  e_lds[128];
  __shared__ float  mb_lds;
  const int tid  = threadIdx.x;
  const int wid  = tid >> 6;           // 0..7
  const int lane = tid & 63;
  const int row0 = blockIdx.x * 128;

  f32x4 fa[8] = {};
  f32x4 fb[8] = {};

  const int ld_r = lane >> 3;
  const int ld_c = (lane & 7) * 8;

  for (int k0 = 0; k0 < DIM; k0 += 64) {
    __syncthreads();
#pragma unroll
    for (int i = 0; i < 2; ++i) {
      const int ch = i * 8 + wid;      // 0..15
      const int r  = ch * 8 + ld_r;    // 0..127
      gload_lds16(Hm + (long)(row0 + r) * DIM + k0 + ld_c, Hs  + ch * 512);
      gload_lds16(Wa + (long)r * DIM        + k0 + ld_c, Was + ch * 512);
      gload_lds16(Wb + (long)r * DIM        + k0 + ld_c, Wbs + ch * 512);
    }
    __syncthreads();
#pragma unroll
    for (int kk = 0; kk < 2; ++kk) {
      const int kc = kk * 32 + (lane >> 4) * 8;
      bf16x8 h = *(const bf16x8*)(Hs + (wid * 16 + (lane & 15)) * 64 + kc);
#pragma unroll
      for (int n = 0; n < 8; ++n) {
        bf16x8 wa = *(const bf16x8*)(Was + (n * 16 + (lane & 15)) * 64 + kc);
        bf16x8 wb = *(const bf16x8*)(Wbs + (n * 16 + (lane & 15)) * 64 + kc);
        fa[n] = __builtin_amdgcn_mfma_f32_16x16x32_bf16(h, wa, fa[n], 0, 0, 0);
        fb[n] = __builtin_amdgcn_mfma_f32_16x16x32_bf16(h, wb, fb[n], 0, 0, 0);
      }
    }
  }

  {
    const int lc = lane & 15;
    const int lq = lane >> 4;
    float g[4];
#pragma unroll
    for (int r = 0; r < 4; ++r) {
      float s = 0.f;
#pragma unroll
      for (int n = 0; n < 8; ++n) {
        float av = fmaxf(fa[n][r], 0.f);
        float sg = 1.f / (1.f + expf(-fb[n][r]));
        s += av * sg * Wc[n * 16 + lc];
      }
      s += __shfl_xor(s, 1);
      s += __shfl_xor(s, 2);
      s += __shfl_xor(s, 4);
      s += __shfl_xor(s, 8);
      g[r] = s;
    }
    if (lc == 0) {
      const int rb = wid * 16 + lq * 4;
#pragma unroll
      for (int r = 0; r < 4; ++r) {
        l_lds[rb + r] = g[r];
        const int nidx = row0 + rb + r;
        if (nidx < NPTS) logits[nidx] = g[r];
      }
    }
  }
  __syncthreads();

  // phase B: block stats (wave 0; fixed-order trees, deterministic)
  if (tid < 64) {
    float a0 = (row0 + tid      < NPTS) ? l_lds[tid]      : -1e30f;
    float a1 = (row0 + 64 + tid < NPTS) ? l_lds[64 + tid] : -1e30f;
    float m = fmaxf(a0, a1);
    for (int o = 32; o > 0; o >>= 1) m = fmaxf(m, __shfl_xor(m, o));
    if (tid == 0) mb_lds = m;
  }
  __syncthreads();
  const float mb = mb_lds;
  if (tid < 128) {
    const int n = row0 + tid;
    e_lds[tid] = (n < NPTS) ? expf(l_lds[tid] - mb) : 0.f;
  }
  __syncthreads();
  if (tid < 64) {
    float s = e_lds[tid] + e_lds[tid + 64];
    for (int o = 32; o > 0; o >>= 1) s += __shfl_xor(s, o);
    if (tid == 0) { part2[blockIdx.x * 2] = mb; part2[blockIdx.x * 2 + 1] = s; }
  }
}

// ---------------- K3: combine 392 block stats -> (M, denom) -------------------
__global__ __launch_bounds__(512)
void comb392_kernel(const float* __restrict__ part2, float* __restrict__ stats) {
  __shared__ float red[512];
  const int tid = threadIdx.x;
  const float m = (tid < NRB) ? part2[tid * 2] : -1e30f;
  red[tid] = m; __syncthreads();
  for (int s = 256; s > 0; s >>= 1) {
    if (tid < s) red[tid] = fmaxf(red[tid], red[tid + s]);
    __syncthreads();
  }
  const float M = red[0];
  __syncthreads();
  red[tid] = (tid < NRB) ? expf(m - M) * part2[tid * 2 + 1] : 0.f;
  __syncthreads();
  for (int s = 256; s > 0; s >>= 1) {
    if (tid < s) red[tid] += red[tid + s];
    __syncthreads();
  }
  if (tid == 0) { stats[0] = M; stats[1] = red[0]; }
}

// ---------------- K4: partial[b][d] = sum_{n in chunk} exp(l_n - M) * h[n][d] --
__global__ __launch_bounds__(192)
void weighted_partial_kernel(const ushort* __restrict__ Hm, const float* __restrict__ logits,
                             const float* __restrict__ stats, float* __restrict__ part) {
  __shared__ float w[128];
  const int b = blockIdx.x, tid = threadIdx.x;
  const int n0 = b * 128;
  if (tid < 128) {
    const int n = n0 + tid;
    w[tid] = (n < NPTS) ? expf(logits[n] - stats[0]) : 0.f;
  }
  __syncthreads();
  float4 acc = {0.f, 0.f, 0.f, 0.f};
  const ushort* hp = Hm + (long)n0 * DIM + tid * 4;
#pragma unroll 4
  for (int r = 0; r < 128; ++r) {
    const float wr = w[r];
    ushort4 v = *(const ushort4*)(hp + (long)r * DIM);
    acc.x += wr * b2f(v.x);
    acc.y += wr * b2f(v.y);
    acc.z += wr * b2f(v.z);
    acc.w += wr * b2f(v.w);
  }
  ((float4*)(part + (long)b * DIM))[tid] = acc;
}

// ---------------- K5: out[d] = (sum_b part[b][d]) / denom ----------------------
__global__ void final_reduce_kernel(const float* __restrict__ part,
                                    const float* __restrict__ stats,
                                    float* __restrict__ out) {
  const int c = blockIdx.x * blockDim.x + threadIdx.x;
  if (c >= DIM) return;
  float s = 0.f;
  for (int b = 0; b < NRB; ++b) s += part[(long)b * DIM + c];
  out[c] = s / stats[1];
}

extern "C" void kernel_launch(void* const* d_in, const int* in_sizes, int n_in,
                              void* d_out, int out_size, void* d_ws, size_t ws_size,
                              hipStream_t stream) {
  const float* x  = (const float*)d_in[0];
  const float* Wf = (const float*)d_in[1];
  const float* bf = (const float*)d_in[2];
  const float* Wa = (const float*)d_in[3];
  const float* Wb = (const float*)d_in[4];
  const float* Wc = (const float*)d_in[5];
  float* out = (float*)d_out;

  char* p = (char*)d_ws;
  ushort* xb  = (ushort*)p; p += (size_t)NPAD * DIM * 2;   // 77.1 MB
  ushort* hb  = (ushort*)p; p += (size_t)NPAD * DIM * 2;   // 77.1 MB
  ushort* wfb = (ushort*)p; p += (size_t)DIM * DIM * 2;
  ushort* wab = (ushort*)p; p += (size_t)DATT * DIM * 2;
  ushort* wbb = (ushort*)p; p += (size_t)DATT * DIM * 2;
  float* logits = (float*)p; p += (size_t)NPAD * 4;
  float* stats  = (float*)p; p += 256;
  float* part2  = (float*)p; p += (size_t)NRB * 2 * 4 + 256;
  float* part   = (float*)p; p += (size_t)NRB * DIM * 4;

  cvt_x_kernel<<<9408, 256, 0, stream>>>(x, xb);
  cvt_weights_kernel<<<384, 256, 0, stream>>>(Wf, Wa, Wb, wfb, wab, wbb);

  gemm_h_kernel<<<196 * 6, 512, 0, stream>>>(xb, wfb, bf, hb);
  gate_stats_kernel<<<NRB, 512, 0, stream>>>(hb, wab, wbb, Wc, logits, part2);
  comb392_kernel<<<1, 512, 0, stream>>>(part2, stats);
  weighted_partial_kernel<<<NRB, 192, 0, stream>>>(hb, logits, stats, part);
  final_reduce_kernel<<<3, 256, 0, stream>>>(part, stats, out);
}